// Round 2
// baseline (3811.861 us; speedup 1.0000x reference)
//
#include <hip/hip_runtime.h>

// Problem constants (fixed by the reference file)
#define NV       29000
#define HW_SHIFT 20                 // H*W = 1024*1024 = 2^20
#define HW_MASK  1048575u
#define BHW      16777216u          // B*H*W = 16 * 2^20
#define PPT      4u                 // pixels per thread
#define BLOCK    256

typedef unsigned int u32;

__global__ __launch_bounds__(BLOCK) void k_zero(float* __restrict__ acc, int n) {
  int i = blockIdx.x * BLOCK + threadIdx.x;
  if (i < n) acc[i] = 0.0f;
}

// Pass 1: segment sums (3 channels) + counts via global float atomics.
// acc layout: [NV][4] = {sum_c0, sum_c1, sum_c2, count}
__global__ __launch_bounds__(BLOCK) void k_accum(const float* __restrict__ img,
                                                 const int* __restrict__ seg,
                                                 float* __restrict__ acc) {
  u32 t  = blockIdx.x * BLOCK + threadIdx.x;
  u32 p0 = t * PPT;
  u32 b  = p0 >> HW_SHIFT;
  u32 hw = p0 & HW_MASK;
  const float* base = img + (((size_t)b * 3) << HW_SHIFT) + hw;

  float4 f0 = *(const float4*)(base);
  float4 f1 = *(const float4*)(base + (1u << HW_SHIFT));
  float4 f2 = *(const float4*)(base + (2u << HW_SHIFT));
  int4  s   = *(const int4*)(seg + p0);

  float c0[4] = { f0.x, f0.y, f0.z, f0.w };
  float c1[4] = { f1.x, f1.y, f1.z, f1.w };
  float c2[4] = { f2.x, f2.y, f2.z, f2.w };
  int   sg[4] = { s.x, s.y, s.z, s.w };

#pragma unroll
  for (int i = 0; i < 4; ++i) {
    float* a = acc + (size_t)sg[i] * 4;
    atomicAdd(a + 0, c0[i]);
    atomicAdd(a + 1, c1[i]);
    atomicAdd(a + 2, c2[i]);
    atomicAdd(a + 3, 1.0f);
  }
}

// Tiny: rep[v][c] = fV[v][c] - sum[v][c] / max(count,1)
__global__ __launch_bounds__(BLOCK) void k_mean(const float* __restrict__ acc,
                                                const float* __restrict__ fV,
                                                float* __restrict__ rep) {
  int v = blockIdx.x * BLOCK + threadIdx.x;
  if (v >= NV) return;
  float cnt = acc[(size_t)v * 4 + 3];
  float inv = 1.0f / fmaxf(cnt, 1.0f);
#pragma unroll
  for (int c = 0; c < 3; ++c) {
    rep[(size_t)v * 3 + c] = fV[(size_t)v * 3 + c] - acc[(size_t)v * 4 + c] * inv;
  }
}

// Pass 2: out[p][c] = pixel[p][c] + rep[seg[p]][c], f32 out, [BHW,3] layout
__global__ __launch_bounds__(BLOCK) void k_inject(const float* __restrict__ img,
                                                  const int* __restrict__ seg,
                                                  const float* __restrict__ rep,
                                                  float* __restrict__ out) {
  u32 t  = blockIdx.x * BLOCK + threadIdx.x;
  u32 p0 = t * PPT;
  u32 b  = p0 >> HW_SHIFT;
  u32 hw = p0 & HW_MASK;
  const float* base = img + (((size_t)b * 3) << HW_SHIFT) + hw;

  float4 f0 = *(const float4*)(base);
  float4 f1 = *(const float4*)(base + (1u << HW_SHIFT));
  float4 f2 = *(const float4*)(base + (2u << HW_SHIFT));
  int4  s   = *(const int4*)(seg + p0);

  float c0[4] = { f0.x, f0.y, f0.z, f0.w };
  float c1[4] = { f1.x, f1.y, f1.z, f1.w };
  float c2[4] = { f2.x, f2.y, f2.z, f2.w };
  int   sg[4] = { s.x, s.y, s.z, s.w };

  float o[12];
#pragma unroll
  for (int i = 0; i < 4; ++i) {
    const float* r = rep + (size_t)sg[i] * 3;
    o[3 * i + 0] = c0[i] + r[0];
    o[3 * i + 1] = c1[i] + r[1];
    o[3 * i + 2] = c2[i] + r[2];
  }

  float4* ob = (float4*)(out + (size_t)p0 * 3);   // p0*3 is a multiple of 12 -> 16B aligned
  ob[0] = make_float4(o[0], o[1], o[2],  o[3]);
  ob[1] = make_float4(o[4], o[5], o[6],  o[7]);
  ob[2] = make_float4(o[8], o[9], o[10], o[11]);
}

extern "C" void kernel_launch(void* const* d_in, const int* in_sizes, int n_in,
                              void* d_out, int out_size, void* d_ws, size_t ws_size,
                              hipStream_t stream) {
  const float* img = (const float*)d_in[0];  // f32 [16,3,1024,1024]
  const int*   seg = (const int*)d_in[1];    // int32 [BHW]
  const float* fV  = (const float*)d_in[2];  // f32 [NV,3]
  // d_in[3] = nV scalar — fixed at 29000 (compile-time constant)
  float* out = (float*)d_out;                // f32 [BHW,3]

  float* acc = (float*)d_ws;                 // [NV][4] sums + count (464 KB)
  float* rep = acc + (size_t)NV * 4;         // [NV][3] replaced_mean (348 KB)

  const u32 nthreads = BHW / PPT;            // 4,194,304
  const u32 nblocks  = nthreads / BLOCK;     // 16,384

  k_zero  <<<(NV * 4 + BLOCK - 1) / BLOCK, BLOCK, 0, stream>>>(acc, NV * 4);
  k_accum <<<nblocks, BLOCK, 0, stream>>>(img, seg, acc);
  k_mean  <<<(NV + BLOCK - 1) / BLOCK, BLOCK, 0, stream>>>(acc, fV, rep);
  k_inject<<<nblocks, BLOCK, 0, stream>>>(img, seg, rep, out);
}